// Round 10
// baseline (11588.921 us; speedup 1.0000x reference)
//
#include <hip/hip_runtime.h>
#include <stdint.h>

#define RB    63          // row-blocks
#define CG    2           // col-groups
#define NWG   (RB * CG)   // 126 WGs, one per CU
#define BLK   1024
#define RPW   32          // rows per WG (63*32 = 2016, 16 pad rows)
#define RDIM  2000
#define KPAD  2048
#define NC    28          // parallel chunks (columns); 14336/28 = 512
#define NCG   (NC / CG)   // 14 cols per col-group
#define CHL   512
#define WARM  112         // echo-state warmup (rho^112 ~ 1e-14)
#define SSTEPS (WARM + CHL)   // 624 sequential steps
#define TT    28
#define NO    10
#define FLAGSTR 16        // flag padding: one per 64B line

static __device__ __forceinline__ unsigned short f32_to_bf16(float f) {
    union { float f; unsigned u; } v; v.f = f;
    unsigned r = v.u + 0x7FFFu + ((v.u >> 16) & 1u);   // RNE
    return (unsigned short)(r >> 16);
}

// 2D-partitioned chunked ESN: WG(r,c2) owns 32 rows x 14 cols of H[2000][28].
// bf16 transport through MALL (relaxed agent atomics), f32 H in 114KB LDS.
// FIX vs R9: outputs fire ONLY in the owned range (j >= WARM) -> each of the
// 512 output rows is produced exactly once (R9 double-added warmup-region
// outputs: absmax 8.75).
__global__ __launch_bounds__(BLK)
void esn_chunked3(const float* __restrict__ x,
                  const float* __restrict__ Win,
                  const float* __restrict__ Wres,
                  const float* __restrict__ Wout,
                  float* __restrict__ out,
                  unsigned short* __restrict__ ws16)
{
    const int tid  = threadIdx.x;
    const int wg   = blockIdx.x;
    const int wgR  = wg >> 1;          // row-block 0..62
    const int c2   = wg & 1;           // col-group 0..1
    const int wv   = tid >> 6;         // wave 0..15
    const int lane = tid & 63;
    const int rq   = wv & 7;           // row-quad 0..7
    const int kh   = wv >> 3;          // k-half 0..1
    const int g16  = lane >> 4;
    const int l16  = lane & 15;
    const int rloc = rq * 4 + g16;     // local row 0..31
    const int row  = wgR * RPW + rloc; // global row (may be >= 2000: pad)
    const int kbase = kh * 1024;

    unsigned short* bufA = ws16;                   // h parity 0 [NC][KPAD]
    unsigned short* bufB = ws16 + NC * KPAD;       // h parity 1
    int* flags = (int*)(ws16 + 2 * NC * KPAD);     // [NWG*FLAGSTR], memset 0

    extern __shared__ float Hdyn[];                // [NCG][KPAD] = 114,688 B
    float (*H)[KPAD] = (float (*)[KPAD])Hdyn;
    __shared__ float x_lds[NCG][32];
    __shared__ float win_lds[RPW][32];
    __shared__ float partial[2][NCG][RPW];
    __shared__ float hnew[NCG][RPW];
    __shared__ float wout_lds[NO][RPW];

    // ---- init ----
    for (int i = tid; i < NCG * KPAD; i += BLK) Hdyn[i] = 0.f;   // h0 = 0
    { int r = tid >> 5, l = tid & 31;
      win_lds[r][l] = (l < TT && (wgR * RPW + r) < RDIM)
                          ? Win[(wgR * RPW + r) * TT + l] : 0.f; }
    if (tid < NO * RPW) {
        int o = tid / RPW, rr = tid % RPW;
        wout_lds[o][rr] = ((wgR * RPW + rr) < RDIM)
                              ? Wout[o * RDIM + wgR * RPW + rr] : 0.f;
    }
    // W_res slice -> registers: lane holds row, k = kbase + cc*64 + l16*4
    float4 wr[16];
    {
        const float* wrow = Wres + (size_t)row * RDIM;
        #pragma unroll
        for (int cc = 0; cc < 16; ++cc) {
            int k = kbase + cc * 64 + l16 * 4;
            wr[cc] = (k < RDIM && row < RDIM) ? *(const float4*)(wrow + k)
                                              : make_float4(0.f, 0.f, 0.f, 0.f);
        }
    }
    __syncthreads();

    for (int j = 0; j < SSTEPS; ++j) {
        // x_t for this WG's 14 cols (cached loads, off the atomic path)
        { int c = tid >> 5, l = tid & 31;
          if (c < NCG && l < TT) {
              int gg = (c2 * NCG + c) * CHL - WARM + j;
              x_lds[c][l] = (gg >= 0 && gg < 14336) ? x[gg * TT + l] : 0.f;
          } }

        // gather: 7 x 1024 u64 words cover 14 cols x 512 words.
        // word w -> col cl = w>>9, widx = w&511; producer = widx>>3.
        // one poller per 8-thread group (same producer); wave lockstep makes
        // the poll cover all 8 lanes. s_sleep backoff.
        const unsigned short* rb = (j & 1) ? bufB : bufA;
        #pragma unroll
        for (int it = 0; it < 7; ++it) {
            const int w    = it * BLK + tid;
            const int cl   = w >> 9;
            const int widx = w & 511;
            if ((tid & 7) == 0) {
                int p = widx >> 3;
                if (p > RB - 1) p = RB - 1;     // pad words: clamp
                while (__hip_atomic_load(&flags[(p * CG + c2) * FLAGSTR],
                                         __ATOMIC_RELAXED,
                                         __HIP_MEMORY_SCOPE_AGENT) < j)
                    __builtin_amdgcn_s_sleep(1);
            }
            const unsigned long long v = __hip_atomic_load(
                (const unsigned long long*)
                    (rb + (size_t)(c2 * NCG + cl) * KPAD + widx * 4),
                __ATOMIC_RELAXED, __HIP_MEMORY_SCOPE_AGENT);
            float4 f;
            f.x = __uint_as_float(((unsigned)( v        & 0xFFFF)) << 16);
            f.y = __uint_as_float(((unsigned)((v >> 16) & 0xFFFF)) << 16);
            f.z = __uint_as_float(((unsigned)((v >> 32) & 0xFFFF)) << 16);
            f.w = __uint_as_float(((unsigned)((v >> 48) & 0xFFFF)) << 16);
            *(float4*)&H[cl][widx * 4] = f;
        }
        __syncthreads();   // barrier 1: H ready

        // matvec: wave (rq,kh) -> 4 rows x 14 cols over its k-half
        #pragma unroll 2
        for (int c = 0; c < NCG; ++c) {
            float a0 = 0.f, a1 = 0.f, a2 = 0.f, a3 = 0.f;
            #pragma unroll
            for (int cc = 0; cc < 16; ++cc) {
                const float4 h4 = *(const float4*)&H[c][kbase + cc * 64 + l16 * 4];
                a0 = fmaf(wr[cc].x, h4.x, a0);
                a1 = fmaf(wr[cc].y, h4.y, a1);
                a2 = fmaf(wr[cc].z, h4.z, a2);
                a3 = fmaf(wr[cc].w, h4.w, a3);
            }
            float acc = (a0 + a1) + (a2 + a3);
            acc += __shfl_down(acc, 8, 16);
            acc += __shfl_down(acc, 4, 16);
            acc += __shfl_down(acc, 2, 16);
            acc += __shfl_down(acc, 1, 16);
            if (l16 == 0) partial[kh][c][rloc] = acc;
        }
        __syncthreads();   // barrier 2: partials ready

        // combine halves + u_t, tanh, pack bf16 pair, agent-store
        unsigned short* wb = (j & 1) ? bufA : bufB;
        if (tid < NCG * RPW / 2) {         // 224 threads, 2 rows each
            const int c = tid >> 4, pr = tid & 15;
            float s0 = partial[0][c][2 * pr]     + partial[1][c][2 * pr];
            float s1 = partial[0][c][2 * pr + 1] + partial[1][c][2 * pr + 1];
            #pragma unroll
            for (int l = 0; l < TT; ++l) {
                const float xl = x_lds[c][l];
                s0 = fmaf(xl, win_lds[2 * pr][l],     s0);
                s1 = fmaf(xl, win_lds[2 * pr + 1][l], s1);
            }
            const float h0 = tanhf(s0), h1 = tanhf(s1);
            hnew[c][2 * pr] = h0; hnew[c][2 * pr + 1] = h1;
            const unsigned pack = (unsigned)f32_to_bf16(h0)
                                | ((unsigned)f32_to_bf16(h1) << 16);
            __hip_atomic_store(
                (unsigned*)(wb + (size_t)(c2 * NCG + c) * KPAD
                               + wgR * RPW + 2 * pr),
                pack, __ATOMIC_RELAXED, __HIP_MEMORY_SCOPE_AGENT);
        }
        __syncthreads();   // barrier 3: all waves' stores drained (vmcnt)

        if (tid == 0)
            __hip_atomic_store(&flags[wg * FLAGSTR], j + 1,
                               __ATOMIC_RELAXED, __HIP_MEMORY_SCOPE_AGENT);

        // outputs: ONLY the owned range j >= WARM (fixes R9 double-add).
        // g = gc*CHL + (j-WARM) is owned by exactly one column; fire when
        // g % 28 == 27. hnew race-free: read after barrier 3, next write is
        // after next step's barrier 2.
        if (j >= WARM && tid < NCG * NO) {
            const int c = tid / NO, o = tid % NO;
            const int g = (c2 * NCG + c) * CHL + (j - WARM);
            if ((g % TT) == TT - 1) {
                const int m = g / TT;
                float s = 0.f;
                #pragma unroll
                for (int rr = 0; rr < RPW; ++rr)
                    s += hnew[c][rr] * wout_lds[o][rr];
                atomicAdd(&out[m * NO + o], s);   // off critical path
            }
        }
    }
}

extern "C" void kernel_launch(void* const* d_in, const int* in_sizes, int n_in,
                              void* d_out, int out_size, void* d_ws, size_t ws_size,
                              hipStream_t stream)
{
    const float* x    = (const float*)d_in[0];
    const float* Win  = (const float*)d_in[1];
    const float* Wres = (const float*)d_in[2];
    const float* Wout = (const float*)d_in[3];
    float* out = (float*)d_out;
    unsigned short* ws16 = (unsigned short*)d_ws;

    // zero h buffers (bf16 zeros) + padded flags; poison must never pass
    hipMemsetAsync(d_ws, 0, (size_t)(2 * NC * KPAD) * sizeof(unsigned short)
                              + (size_t)NWG * FLAGSTR * sizeof(int), stream);
    hipMemsetAsync(d_out, 0, (size_t)out_size * sizeof(float), stream);

    (void)hipFuncSetAttribute((const void*)esn_chunked3,
                              hipFuncAttributeMaxDynamicSharedMemorySize,
                              NCG * KPAD * (int)sizeof(float));

    hipLaunchKernelGGL(esn_chunked3, dim3(NWG), dim3(BLK),
                       NCG * KPAD * sizeof(float), stream,
                       x, Win, Wres, Wout, out, ws16);
}